// Round 6
// baseline (336.502 us; speedup 1.0000x reference)
//
#include <hip/hip_runtime.h>
#include <hip/hip_bf16.h>

#define EPS 1e-6f
#define INV_TEMP 0.31622776601683794f   // 1/sqrt(10), folded into Wq fragments

typedef float f32x4 __attribute__((ext_vector_type(4)));
typedef short short8v __attribute__((ext_vector_type(8)));
typedef unsigned uint4v __attribute__((ext_vector_type(4)));

#define MFMA(a,b,c) __builtin_amdgcn_mfma_f32_16x16x32_bf16(a,b,c,0,0,0)

// ---------- B-fragment table in d_ws (bf16 shorts), 52 frags x 512 shorts ----------
// f=0..2: Wq(scaled),Wk,Wv (K=10,N=10)   f=3,4: W1 nt0,1 (K=30,N=30)
// f=5,6: W2 nt0,1                        f=7+kt*6+nt  : W1p (K=90,N=90)
// f=25+kt*6+nt: W2p                      f=43+kt*3+nt : Wc1 (K=90,N=45)
// prep zeroes all out-of-range K/N entries -> A-fragment k-pad contributes 0
// provided it is FINITE (pads explicitly zeroed below).
#define NFRAG 52

// ---------- per-wave LDS layout (offsets in shorts) ----------
#define X30   0        // [48 x 40] branch rows (b*16+r), feats s*10+d; shorts 30,31 = 0
#define PROJ  1920     // [48 x 40] stage3 A-repack; aliases H30, H90[16x104], C1T[16x48]
#define QH    3840     // [48 x 14]; QH/KH/VH alias X90 [16 x 104]
#define KH    4512
#define VH    5184
#define X90   3840
#define H30   1920
#define H90   1920
#define C1T   1920
#define WSM   5856     // shorts per wave = 11712 B

#define S_P   40       // 80 B rows (16B-aligned)
#define S_Q   14
#define S_X9  104      // 208 B rows (16B-aligned)
#define S_C1  48

__device__ __forceinline__ unsigned short f2b_sw(float x){       // RNE (prep)
  unsigned u = __float_as_uint(x);
  u += 0x7fffu + ((u>>16)&1u);
  return (unsigned short)(u>>16);
}
__device__ __forceinline__ unsigned pack2(float a, float b){     // low=a, high=b, RNE
  float2 t; t.x = a; t.y = b;
  __hip_bfloat162 h = __float22bfloat162_rn(t);
  unsigned u; __builtin_memcpy(&u, &h, 4); return u;
}
__device__ __forceinline__ unsigned short f2b(float x){
  __hip_bfloat16 h = __float2bfloat16(x);
  unsigned short u; __builtin_memcpy(&u, &h, 2); return u;
}
__device__ __forceinline__ float b2f(unsigned u16){
  return __uint_as_float(u16<<16);
}
__device__ __forceinline__ short8v ldB(const unsigned short* __restrict__ wf, int f, int wtid){
  return *(const short8v*)(wf + f*512 + wtid*8);
}
__device__ __forceinline__ short8v ldA(const unsigned short* sm, int rowbase, int stride, int koff, int wtid){
  return *(const short8v*)(sm + (rowbase + (wtid&15))*stride + koff + (wtid>>4)*8);
}
__device__ __forceinline__ float qsum16(float v){
  v += __shfl_xor(v,1,64); v += __shfl_xor(v,2,64);
  v += __shfl_xor(v,4,64); v += __shfl_xor(v,8,64);
  return v;
}

// ---------------- prep: bake weights into B-fragment order ----------------
__global__ void prep_kernel(const float* __restrict__ Wq, const float* __restrict__ Wk,
                            const float* __restrict__ Wv, const float* __restrict__ W1,
                            const float* __restrict__ W2, const float* __restrict__ W1p,
                            const float* __restrict__ W2p, const float* __restrict__ Wc1,
                            unsigned short* __restrict__ wf)
{
  int t = blockIdx.x*blockDim.x + threadIdx.x;
  if (t >= NFRAG*512) return;
  int f = t>>9, e = t&511, lane = e>>3, j = e&7;
  int n = lane&15, kk = (lane>>4)*8 + j;
  const float* src; int K, N, kt, nt; float scale = 1.f;
  if (f < 3)      { src = (f==0)?Wq:(f==1)?Wk:Wv; K=10; N=10; kt=0; nt=0; if (f==0) scale=INV_TEMP; }
  else if (f < 5) { src = W1;  K=30; N=30; kt=0; nt=f-3; }
  else if (f < 7) { src = W2;  K=30; N=30; kt=0; nt=f-5; }
  else if (f < 25){ int g=f-7;  src = W1p; K=90; N=90; kt=g/6; nt=g%6; }
  else if (f < 43){ int g=f-25; src = W2p; K=90; N=90; kt=g/6; nt=g%6; }
  else            { int g=f-43; src = Wc1; K=90; N=45; kt=g/3; nt=g%3; }
  int gn = nt*16 + n, gk = kt*32 + kk;
  float v = (gn < N && gk < K) ? src[gn*K + gk]*scale : 0.f;   // B[k][n] = W[n][k]
  wf[t] = f2b_sw(v);
}

// ---------------- attention on one branch (lanes 0..47); residual from X30 ----------------
__device__ __forceinline__ void attn_phase(unsigned short* sm, int wtid, int b,
    const float* __restrict__ g, const float* __restrict__ bb)
{
  if (wtid >= 48) return;
  int r = wtid/3, s = wtid - 3*r;
  float qv[10], ov[10], at[3];
  { const unsigned* p = (const unsigned*)(sm + QH + wtid*S_Q);
    #pragma unroll
    for (int e=0;e<5;++e){ unsigned u=p[e]; qv[2*e]=b2f(u&0xffffu); qv[2*e+1]=b2f(u>>16); } }
  #pragma unroll
  for (int t=0;t<3;++t){
    const unsigned* p = (const unsigned*)(sm + KH + (r*3+t)*S_Q);
    float a = 0.f;
    #pragma unroll
    for (int e=0;e<5;++e){ unsigned u=p[e];
      a = fmaf(qv[2*e],   b2f(u&0xffffu), a);
      a = fmaf(qv[2*e+1], b2f(u>>16),    a); }
    at[t] = a;                                  // qh pre-scaled by 1/sqrt(10)
  }
  { const unsigned* p = (const unsigned*)(sm + X30 + (b*16+r)*S_P + s*10);
    #pragma unroll
    for (int e=0;e<5;++e){ unsigned u=p[e]; ov[2*e]=b2f(u&0xffffu); ov[2*e+1]=b2f(u>>16); } }
  #pragma unroll
  for (int t=0;t<3;++t){
    const unsigned* p = (const unsigned*)(sm + VH + (r*3+t)*S_Q);
    #pragma unroll
    for (int e=0;e<5;++e){ unsigned u=p[e];
      ov[2*e]   = fmaf(at[t], b2f(u&0xffffu), ov[2*e]);
      ov[2*e+1] = fmaf(at[t], b2f(u>>16),    ov[2*e+1]); }
  }
  float sum=0.f, sq=0.f;
  #pragma unroll
  for (int d=0;d<10;++d){ sum += ov[d]; sq = fmaf(ov[d],ov[d],sq); }
  float mm = sum*0.1f, rs = rsqrtf(sq*0.1f - mm*mm + EPS);
  unsigned* wp = (unsigned*)(sm + X30 + (b*16+r)*S_P + s*10);
  #pragma unroll
  for (int e=0;e<5;++e){
    float z0 = fmaf((ov[2*e]-mm)*rs,   g[2*e],   bb[2*e]);
    float z1 = fmaf((ov[2*e+1]-mm)*rs, g[2*e+1], bb[2*e+1]);
    wp[e] = pack2(z0, z1);
  }
}

// ---------------- PFF30 on all 48 branch-rows; to_x90 selects output layout ----------------
__device__ __forceinline__ void pff30(unsigned short* sm, int wtid, const unsigned short* __restrict__ wf,
  const float* __restrict__ b1, const float* __restrict__ b2,
  const float* __restrict__ g, const float* __restrict__ bb, int to_x90)
{
  const int m15 = wtid & 15, quad = wtid >> 4;
  const bool c1ok = (m15 < 14);                 // col 16+m15 < 30
  float bi0 = b1[m15], bi1 = c1ok ? b1[16+m15] : 0.f;
  float b20 = b2[m15], b21 = c1ok ? b2[16+m15] : 0.f;
  float g0  = g[m15],  g1  = c1ok ? g[16+m15]  : 0.f;
  float e0  = bb[m15], e1  = c1ok ? bb[16+m15] : 0.f;
  short8v B10 = ldB(wf,3,wtid), B11 = ldB(wf,4,wtid), B20 = ldB(wf,5,wtid), B21 = ldB(wf,6,wtid);
  #pragma unroll 1
  for (int mt=0; mt<3; ++mt){
    short8v A = ldA(sm + X30, mt*16, S_P, 0, wtid);
    f32x4 C0 = {0.f,0.f,0.f,0.f}, C1 = {0.f,0.f,0.f,0.f};
    C0 = MFMA(A, B10, C0);
    C1 = MFMA(A, B11, C1);
    #pragma unroll
    for (int rg=0; rg<4; ++rg){
      int row = mt*16 + quad*4 + rg;
      sm[H30 + row*S_P + m15]    = f2b(fmaxf(C0[rg]+bi0, 0.f));
      sm[H30 + row*S_P + 16+m15] = f2b(fmaxf(C1[rg]+bi1, 0.f));  // cols 30,31 -> 0
    }
    short8v A2 = ldA(sm + H30, mt*16, S_P, 0, wtid);
    f32x4 D0 = {0.f,0.f,0.f,0.f}, D1 = {0.f,0.f,0.f,0.f};
    D0 = MFMA(A2, B20, D0);
    D1 = MFMA(A2, B21, D1);
    float y0[4], y1[4];
    #pragma unroll
    for (int rg=0; rg<4; ++rg){
      int row = mt*16 + quad*4 + rg;
      float r0 = b2f(sm[X30 + row*S_P + m15]);
      float r1 = c1ok ? b2f(sm[X30 + row*S_P + 16+m15]) : 0.f;
      y0[rg] = D0[rg] + b20 + r0;
      y1[rg] = c1ok ? (D1[rg] + b21 + r1) : 0.f;
    }
    #pragma unroll
    for (int rg=0; rg<4; ++rg){
      float sr = qsum16(y0[rg] + y1[rg]);
      float qr = qsum16(y0[rg]*y0[rg] + y1[rg]*y1[rg]);
      float mm = sr * (1.f/30.f);
      float rs = rsqrtf(qr*(1.f/30.f) - mm*mm + EPS);
      float z0 = fmaf((y0[rg]-mm)*rs, g0, e0);
      float z1 = fmaf((y1[rg]-mm)*rs, g1, e1);   // 0 when !c1ok
      if (!to_x90){
        int row = mt*16 + quad*4 + rg;
        sm[X30 + row*S_P + m15]    = f2b(z0);
        sm[X30 + row*S_P + 16+m15] = f2b(z1);    // cols 30,31 stay 0
      } else {
        int rr = quad*4 + rg;                    // brow = mt*16+rr -> x90[rr][mt*30+col]
        sm[X90 + rr*S_X9 + mt*30 + m15]    = f2b(z0);
        sm[X90 + rr*S_X9 + mt*30 + 16+m15] = f2b(z1);
      }
    }
  }
}

// ---------------- main: 128 threads = 2 independent waves, 16 rows each ----------------
__global__ __launch_bounds__(128, 3) void moct_kernel(
  const float* __restrict__ q, const float* __restrict__ k, const float* __restrict__ v,
  const float* __restrict__ g_mha, const float* __restrict__ b_mha,
  const float* __restrict__ b1, const float* __restrict__ b2,
  const float* __restrict__ g_pff, const float* __restrict__ b_pff,
  const float* __restrict__ b1p, const float* __restrict__ b2p,
  const float* __restrict__ g_pff1, const float* __restrict__ b_pff1,
  const float* __restrict__ bc1, const float* __restrict__ Wc2, const float* __restrict__ bc2,
  const unsigned short* __restrict__ wf,
  float* __restrict__ out)
{
  __shared__ __align__(16) unsigned short smem[2*WSM];
  const int tid = threadIdx.x, wv = tid>>6, wtid = tid&63;
  unsigned short* sm = smem + wv*WSM;
  const int m15 = wtid & 15, quad = wtid >> 4;
  const int row0 = blockIdx.x*32 + wv*16;

  // X30 k-pad (shorts 30,31 per row) = 0 once; never overwritten after.
  if (wtid < 48) *(unsigned*)(sm + X30 + wtid*S_P + 30) = 0u;

  short8v Bq = ldB(wf,0,wtid), Bk = ldB(wf,1,wtid), Bv = ldB(wf,2,wtid);

  // ---- two MHA+PFF30 passes (pass0: from global q/k/v; pass1: self-attn on x30) ----
  #pragma unroll 1
  for (int pass = 0; pass < 2; ++pass){
    #pragma unroll 1
    for (int b = 0; b < 3; ++b){
      if (pass == 0){
        #pragma unroll 1
        for (int w = 0; w < 3; ++w){
          const float* T = (w==0)?q:(w==1)?k:v;
          short8v Bf = (w==0)?Bq:(w==1)?Bk:Bv;
          #pragma unroll
          for (int mt = 0; mt < 3; ++mt){
            int sr = mt*16 + m15, rl = sr/3, s = sr - 3*rl;
            const float* src = T + (size_t)(row0+rl)*90 + b*30 + s*10;
            unsigned a0=0u, a1=0u, a2=0u, a3=0u;
            if (quad == 0){
              const float2* sp = (const float2*)src;
              float2 u0=sp[0], u1=sp[1], u2=sp[2], u3=sp[3];
              a0=pack2(u0.x,u0.y); a1=pack2(u1.x,u1.y);
              a2=pack2(u2.x,u2.y); a3=pack2(u3.x,u3.y);
            } else if (quad == 1){
              float2 u = ((const float2*)src)[4];
              a0 = pack2(u.x,u.y);                 // k=8,9; rest zero (B rows k>=10 are 0)
            }
            if (w == 0){                           // bf16 q residual -> X30
              unsigned* rp = (unsigned*)(sm + X30 + (b*16+rl)*S_P + s*10);
              if (quad == 0){ rp[0]=a0; rp[1]=a1; rp[2]=a2; rp[3]=a3; }
              else if (quad == 1){ rp[4]=a0; }
            }
            uint4v av = {a0,a1,a2,a3};
            short8v A; __builtin_memcpy(&A, &av, 16);
            f32x4 c = {0.f,0.f,0.f,0.f};
            c = MFMA(A, Bf, c);
            if (m15 < 10){
              #pragma unroll
              for (int rg=0; rg<4; ++rg)
                sm[QH + w*672 + (mt*16+quad*4+rg)*S_Q + m15] = f2b(c[rg]);
            }
          }
        }
      } else {
        if (wtid < 48){   // repack x30 branch b -> PROJ seq-rows
          int r = wtid/3, s = wtid - 3*r;
          const unsigned* sp = (const unsigned*)(sm + X30 + (b*16+r)*S_P + s*10);
          unsigned* dp = (unsigned*)(sm + PROJ + wtid*S_P);
          #pragma unroll
          for (int e=0; e<5; ++e) dp[e] = sp[e];
        }
        #pragma unroll 1
        for (int mt = 0; mt < 3; ++mt){
          short8v A = ldA(sm+PROJ, mt*16, S_P, 0, wtid);
          f32x4 c0={0.f,0.f,0.f,0.f}, c1={0.f,0.f,0.f,0.f}, c2={0.f,0.f,0.f,0.f};
          c0 = MFMA(A,Bq,c0); c1 = MFMA(A,Bk,c1); c2 = MFMA(A,Bv,c2);
          if (m15 < 10){
            #pragma unroll
            for (int rg=0; rg<4; ++rg){
              int rw = mt*16 + quad*4 + rg;
              sm[QH + rw*S_Q + m15] = f2b(c0[rg]);
              sm[KH + rw*S_Q + m15] = f2b(c1[rg]);
              sm[VH + rw*S_Q + m15] = f2b(c2[rg]);
            }
          }
        }
      }
      attn_phase(sm, wtid, b, g_mha, b_mha);
    }
    if (pass == 1 && wtid < 48){
      // X90 pad shorts 90..95 (words 45..47 per row) = 0; region aliased QKV until now
      int rr = wtid/3, wd = wtid - 3*rr;
      ((unsigned*)sm)[1920 + rr*52 + 45 + wd] = 0u;
    }
    pff30(sm, wtid, wf, b1, b2, g_pff, b_pff, pass);
  }

  // ---- stage 5: PFF90 (x90 in-place; H90 in PROJ) ----
  {
    short8v A0 = ldA(sm+X90, 0, S_X9, 0,  wtid);
    short8v A1 = ldA(sm+X90, 0, S_X9, 32, wtid);
    short8v A2 = ldA(sm+X90, 0, S_X9, 64, wtid);
    #pragma unroll 1
    for (int nt=0; nt<6; ++nt){
      f32x4 c = {0.f,0.f,0.f,0.f};
      c = MFMA(A0, ldB(wf, 7+nt,  wtid), c);
      c = MFMA(A1, ldB(wf, 13+nt, wtid), c);
      c = MFMA(A2, ldB(wf, 19+nt, wtid), c);
      int col = nt*16 + m15;
      float bi = (col < 90) ? b1p[col] : 0.f;
      #pragma unroll
      for (int rg=0; rg<4; ++rg)
        sm[H90 + (quad*4+rg)*S_X9 + col] = f2b(fmaxf(c[rg]+bi, 0.f));  // cols>=90 -> 0
    }
    short8v H0 = ldA(sm+H90, 0, S_X9, 0,  wtid);
    short8v H1 = ldA(sm+H90, 0, S_X9, 32, wtid);
    short8v H2 = ldA(sm+H90, 0, S_X9, 64, wtid);
    float y[6][4];
    #pragma unroll
    for (int nt=0; nt<6; ++nt){
      f32x4 d = {0.f,0.f,0.f,0.f};
      d = MFMA(H0, ldB(wf, 25+nt, wtid), d);
      d = MFMA(H1, ldB(wf, 31+nt, wtid), d);
      d = MFMA(H2, ldB(wf, 37+nt, wtid), d);
      int col = nt*16 + m15;
      bool ok = (col < 90);
      float b2v = ok ? b2p[col] : 0.f;
      #pragma unroll
      for (int rg=0; rg<4; ++rg){
        float rv = ok ? b2f(sm[X90 + (quad*4+rg)*S_X9 + col]) : 0.f;
        y[nt][rg] = ok ? (d[rg] + b2v + rv) : 0.f;
      }
    }
    #pragma unroll
    for (int rg=0; rg<4; ++rg){
      float ps = 0.f, pq = 0.f;
      #pragma unroll
      for (int nt=0; nt<6; ++nt){ ps += y[nt][rg]; pq = fmaf(y[nt][rg], y[nt][rg], pq); }
      float sr = qsum16(ps), qr = qsum16(pq);
      float mm = sr*(1.f/90.f);
      float rs = rsqrtf(qr*(1.f/90.f) - mm*mm + EPS);
      int row = quad*4 + rg;
      #pragma unroll
      for (int nt=0; nt<6; ++nt){
        int col = nt*16 + m15;
        if (col < 90)
          sm[X90 + row*S_X9 + col] = f2b(fmaf((y[nt][rg]-mm)*rs, g_pff1[col], b_pff1[col]));
      }
    }
  }

  // ---- classifier + softmax ----
  {
    short8v A0 = ldA(sm+X90, 0, S_X9, 0,  wtid);
    short8v A1 = ldA(sm+X90, 0, S_X9, 32, wtid);
    short8v A2 = ldA(sm+X90, 0, S_X9, 64, wtid);
    #pragma unroll 1
    for (int nt=0; nt<3; ++nt){
      f32x4 c = {0.f,0.f,0.f,0.f};
      c = MFMA(A0, ldB(wf, 43+nt, wtid), c);
      c = MFMA(A1, ldB(wf, 46+nt, wtid), c);
      c = MFMA(A2, ldB(wf, 49+nt, wtid), c);
      int col = nt*16 + m15;
      float bi = (col < 45) ? bc1[col] : 0.f;
      #pragma unroll
      for (int rg=0; rg<4; ++rg)
        sm[C1T + (quad*4+rg)*S_C1 + col] = f2b(fmaxf(c[rg]+bi, 0.f));
    }
    int row = m15, p = quad;
    int i0 = p*12, cnt = (p<3) ? 12 : 9;
    float lg0=0.f, lg1=0.f, lg2=0.f;
    for (int ii=0; ii<cnt; ++ii){
      float cv = b2f(sm[C1T + row*S_C1 + i0+ii]);
      lg0 = fmaf(cv, Wc2[     i0+ii], lg0);
      lg1 = fmaf(cv, Wc2[45 + i0+ii], lg1);
      lg2 = fmaf(cv, Wc2[90 + i0+ii], lg2);
    }
    lg0 += __shfl_xor(lg0,16,64); lg0 += __shfl_xor(lg0,32,64);
    lg1 += __shfl_xor(lg1,16,64); lg1 += __shfl_xor(lg1,32,64);
    lg2 += __shfl_xor(lg2,16,64); lg2 += __shfl_xor(lg2,32,64);
    lg0 += bc2[0]; lg1 += bc2[1]; lg2 += bc2[2];
    float mx = fmaxf(lg0, fmaxf(lg1,lg2));
    float x0 = __expf(lg0-mx), x1 = __expf(lg1-mx), x2 = __expf(lg2-mx);
    float inv = 1.f/(x0+x1+x2);
    if (p == 0){
      float* o = out + (size_t)(row0+row)*3;
      o[0]=x0*inv; o[1]=x1*inv; o[2]=x2*inv;
    }
  }
}

extern "C" void kernel_launch(void* const* d_in, const int* in_sizes, int n_in,
                              void* d_out, int out_size, void* d_ws, size_t ws_size,
                              hipStream_t stream)
{
  const float* q     = (const float*)d_in[0];
  const float* k     = (const float*)d_in[1];
  const float* v     = (const float*)d_in[2];
  const float* Wq    = (const float*)d_in[3];
  const float* Wk    = (const float*)d_in[4];
  const float* Wv    = (const float*)d_in[5];
  const float* g_mha = (const float*)d_in[6];
  const float* b_mha = (const float*)d_in[7];
  const float* W1    = (const float*)d_in[8];
  const float* b1    = (const float*)d_in[9];
  const float* W2    = (const float*)d_in[10];
  const float* b2    = (const float*)d_in[11];
  const float* g_pff = (const float*)d_in[12];
  const float* b_pff = (const float*)d_in[13];
  const float* W1p   = (const float*)d_in[14];
  const float* b1p   = (const float*)d_in[15];
  const float* W2p   = (const float*)d_in[16];
  const float* b2p   = (const float*)d_in[17];
  const float* g_pff1= (const float*)d_in[18];
  const float* b_pff1= (const float*)d_in[19];
  const float* Wc1   = (const float*)d_in[20];
  const float* bc1   = (const float*)d_in[21];
  const float* Wc2   = (const float*)d_in[22];
  const float* bc2   = (const float*)d_in[23];

  unsigned short* wf = (unsigned short*)d_ws;
  const int nrows = in_sizes[0] / 90;

  hipLaunchKernelGGL(prep_kernel, dim3((NFRAG*512 + 255)/256), dim3(256), 0, stream,
                     Wq, Wk, Wv, W1, W2, W1p, W2p, Wc1, wf);

  hipLaunchKernelGGL(moct_kernel, dim3(nrows/32), dim3(128), 0, stream,
    q, k, v, g_mha, b_mha, b1, b2, g_pff, b_pff,
    b1p, b2p, g_pff1, b_pff1, bc1, Wc2, bc2, wf, (float*)d_out);
}